// Round 7
// baseline (242.698 us; speedup 1.0000x reference)
//
#include <hip/hip_runtime.h>
#include <stdint.h>

#define NROWS 16384   // 16*32*32 spatial positions
#define NCODES 8192
#define DIM 256
// score = 1024 + dot - ||e||^2/2  (higher = closer). bf16 dist-error sigma
// ~0.05 in score units. EPS_S = 0.4 (8 sigma one-sided); SM = 0.8.
// Validated absmax=0 in R4/R5/R6.
#define EPS_S 0.4f
#define SM 0.8f

typedef __attribute__((ext_vector_type(8))) short bf16x8;  // 8 bf16 = 4 VGPRs
typedef __attribute__((ext_vector_type(4))) float f32x4;
typedef unsigned int uint32;

__device__ __forceinline__ unsigned short f2bf(float f) {
  union { float f; unsigned int u; } v; v.f = f;
  unsigned int u = v.u;
  return (unsigned short)((u + 0x7FFFu + ((u >> 16) & 1u)) >> 16);  // RNE
}

__device__ __forceinline__ void glds16(const void* g, void* l) {
  __builtin_amdgcn_global_load_lds(
      (const __attribute__((address_space(1))) unsigned int*)g,
      (__attribute__((address_space(3))) unsigned int*)l, 16, 0, 0);
}

// exact-path u64 key = order-preserving dist bits << 32 | idx (min = best+lowest idx)
__device__ __forceinline__ unsigned long long packdi(float d, int idx) {
  unsigned int u = __float_as_uint(d);
  u = (u & 0x80000000u) ? ~u : (u | 0x80000000u);
  return ((unsigned long long)u << 32) | (unsigned int)idx;
}
__device__ __forceinline__ unsigned long long u64min(unsigned long long a,
                                                     unsigned long long b) {
  return a < b ? a : b;
}
__device__ __forceinline__ unsigned long long shflx64(unsigned long long v, int m) {
  int lo = __shfl_xor((int)(unsigned int)v, m);
  int hi = __shfl_xor((int)(v >> 32), m);
  return ((unsigned long long)(unsigned int)hi << 32) | (unsigned int)lo;
}
__device__ __forceinline__ uint32 umax(uint32 a, uint32 b) { return a > b ? a : b; }
__device__ __forceinline__ uint32 umin(uint32 a, uint32 b) { return a < b ? a : b; }

// ---- Phase 0 (fused): z transpose+bf16, codebook bf16+norms ----------------
__global__ __launch_bounds__(256) void prep(const float* __restrict__ z,
                                            const float* __restrict__ cb,
                                            float* __restrict__ flatz,
                                            ushort* __restrict__ zb,
                                            ushort* __restrict__ eb,
                                            float* __restrict__ enorm) {
  __shared__ float t[32][33];
  const int blk = blockIdx.x;
  if (blk < 4096) {  // prep_z part: NCHW -> (row, d), fp32 copy into zq
    const int tx = threadIdx.x & 31, ty = threadIdx.x >> 5;  // 32 x 8
    const int ht = blk & 31, ct = (blk >> 5) & 7, b = blk >> 8;
    const float* src = z + (size_t)b * 262144 + (size_t)(ct * 32) * 1024 + ht * 32;
#pragma unroll
    for (int i = 0; i < 4; ++i) {
      int c = ty + i * 8;
      t[c][tx] = src[c * 1024 + tx];
    }
    __syncthreads();
#pragma unroll
    for (int i = 0; i < 4; ++i) {
      int hw = ty + i * 8;
      int row = b * 1024 + ht * 32 + hw;
      float v = t[tx][hw];
      flatz[(size_t)row * 256 + ct * 32 + tx] = v;
      zb[(size_t)row * 256 + ct * 32 + tx] = f2bf(v);
    }
  } else {  // prep_cb part
    const int lane = threadIdx.x & 63, wave = threadIdx.x >> 6;
    const int code = (blk - 4096) * 4 + wave;
    float4 v = *(const float4*)(cb + (size_t)code * 256 + lane * 4);
    ushort4 o;
    o.x = f2bf(v.x); o.y = f2bf(v.y); o.z = f2bf(v.z); o.w = f2bf(v.w);
    *(ushort4*)(eb + (size_t)code * 256 + lane * 4) = o;
    float ss = v.x * v.x + v.y * v.y + v.z * v.z + v.w * v.w;
#pragma unroll
    for (int s = 1; s < 64; s <<= 1) ss += __shfl_xor(ss, s);
    if (lane == 0) enorm[code] = ss;
  }
}

// ---- Phase 1: bf16 MFMA score GEMM — barrier-free K-loop -------------------
// A (128 codes x full K=256) staged ONCE into 64 KB LDS (one barrier total);
// B (256 zrows) read global->VGPR per iter with next-iter register prefetch.
// 4 waves = (wr: code half) x (wc: zrow half), each 64 codes x 128 zrows as
// 4i x 8j frags of 16x16x32. LDS A-swizzle: 16B chunk c of row r stored at
// slot c ^ (r&7)  -> b128 reads are 2-way (free); glds writes linear (free).
// Epilogue (R5-validated): per 16-code chunk u32: score&~31 | flag<<4 | id.
__global__ __launch_bounds__(256, 2) void vq_gemm(const ushort* __restrict__ eb,
                                                  const ushort* __restrict__ zb,
                                                  const float* __restrict__ enorm,
                                                  uint32* __restrict__ bm) {
  __shared__ __align__(16) ushort As[128 * 256];  // full-K A, 64 KB
  const int tid = threadIdx.x;
  const int wave = tid >> 6, lane = tid & 63;
  const int wr = wave >> 1, wc = wave & 1;  // code half / zrow half
  const int code0 = blockIdx.x * 128;
  const int zrow0 = blockIdx.y * 256;
  const int q = lane >> 4, l15 = lane & 15;

  // ---- stage full-K A: wave w round t covers rows t*8 + w*2 + (lane>>5) ----
  {
    const int rl = lane >> 5;      // 0/1
    const int s = lane & 31;       // chunk slot within row
#pragma unroll
    for (int t = 0; t < 16; ++t) {
      int r = t * 8 + wave * 2 + rl;
      int c = s ^ (r & 7);         // global chunk for this slot (XOR swizzle)
      glds16(eb + (size_t)(code0 + r) * 256 + c * 8,
             &As[(t * 8 + wave * 2) * 256]);
    }
  }

  // acc init: 1024 - 0.5*||e||^2 (score trick) replicated across 8 j-frags
  f32x4 acc[4][8];
#pragma unroll
  for (int i = 0; i < 4; ++i) {
    float4 e = *(const float4*)(enorm + code0 + wr * 64 + i * 16 + q * 4);
    f32x4 c0 = {1024.f - 0.5f * e.x, 1024.f - 0.5f * e.y,
                1024.f - 0.5f * e.z, 1024.f - 0.5f * e.w};
#pragma unroll
    for (int j = 0; j < 8; ++j) acc[i][j] = c0;
  }

  // B bases: frag j = zrows zrow0+wc*128+j*16..+15; lane reads 16B at row
  // l15, k-offset q*8 (+k0*32/iter). Wave collectively = 16 full 64B lines.
  const ushort* bG[8];
#pragma unroll
  for (int j = 0; j < 8; ++j)
    bG[j] = zb + (size_t)(zrow0 + wc * 128 + j * 16 + l15) * 256 + q * 8;

  // prologue B(k0=0) issued before the barrier to overlap the glds drain
  bf16x8 bcur[8], bnxt[8];
#pragma unroll
  for (int j = 0; j < 8; ++j) bcur[j] = *(const bf16x8*)(bG[j]);

  __syncthreads();  // the ONLY barrier: A fully staged (drains glds)

#pragma unroll
  for (int k0 = 0; k0 < 8; ++k0) {
    if (k0 < 7) {
#pragma unroll
      for (int j = 0; j < 8; ++j)
        bnxt[j] = *(const bf16x8*)(bG[j] + (k0 + 1) * 32);
    }
    bf16x8 af[4];
#pragma unroll
    for (int i = 0; i < 4; ++i) {
      int R = wr * 64 + i * 16 + l15;
      int slot = ((k0 * 4 + q) ^ (l15 & 7)) * 8;  // un-swizzle
      af[i] = *(const bf16x8*)(&As[R * 256 + slot]);
    }
#pragma unroll
    for (int i = 0; i < 4; ++i)
#pragma unroll
      for (int j = 0; j < 8; ++j)
        acc[i][j] = __builtin_amdgcn_mfma_f32_16x16x32_bf16(af[i], bcur[j],
                                                            acc[i][j], 0, 0, 0);
#pragma unroll
    for (int j = 0; j < 8; ++j) bcur[j] = bnxt[j];
  }

  // epilogue (R5 math, j extended to 8): C/D col=lane&15 (zrow), row=q*4+r.
  // Per i-frag (16 codes): pack id low 4 bits, top-2 chains, flag bit 4 =
  // in-chunk gap > SM. bm[zr][chunk16].
  const int cid0 = blockIdx.x * 8 + wr * 4;
#pragma unroll
  for (int j = 0; j < 8; ++j) {
    uint32 res[4];
#pragma unroll
    for (int i = 0; i < 4; ++i) {
      uint32 pv0 = (__float_as_uint(acc[i][j][0]) & ~31u) | (uint32)(q * 4 + 0);
      uint32 pv1 = (__float_as_uint(acc[i][j][1]) & ~31u) | (uint32)(q * 4 + 1);
      uint32 pv2 = (__float_as_uint(acc[i][j][2]) & ~31u) | (uint32)(q * 4 + 2);
      uint32 pv3 = (__float_as_uint(acc[i][j][3]) & ~31u) | (uint32)(q * 4 + 3);
      uint32 x01 = umax(pv0, pv1), n01 = umin(pv0, pv1);
      uint32 x23 = umax(pv2, pv3), n23 = umin(pv2, pv3);
      uint32 m1 = umax(x01, x23);
      uint32 m2 = umax(umin(x01, x23), umax(n01, n23));
#pragma unroll
      for (int m = 16; m < 64; m <<= 1) {  // merge the 4 q-groups
        uint32 o1 = (uint32)__shfl_xor((int)m1, m);
        uint32 o2 = (uint32)__shfl_xor((int)m2, m);
        m2 = umax(umax(m2, o2), umin(m1, o1));
        m1 = umax(m1, o1);
      }
      float s1 = __uint_as_float(m1 & ~31u);
      float s2 = __uint_as_float(m2 & ~31u);
      res[i] = (s1 - s2 > SM) ? (m1 | 16u) : m1;
    }
    if (lane < 16) {
      int zr = zrow0 + wc * 128 + j * 16 + l15;
      uint4 o; o.x = res[0]; o.y = res[1]; o.z = res[2]; o.w = res[3];
      *(uint4*)(bm + (size_t)zr * 512 + cid0) = o;
    }
  }
}

// exact fp32 distances for one 16-code chunk; summation order / lane split /
// tie-break bit-identical to the R2..R6-validated slow path.
__device__ __forceinline__ unsigned long long chunk_exact(
    int chunk, const float* __restrict__ zrow, const float* __restrict__ cb,
    const float* __restrict__ enorm, int lane) {
  const int code = chunk * 16 + (lane >> 2);
  const float* zp = zrow + (lane & 3) * 64;
  const float* cp = cb + (size_t)code * 256 + (lane & 3) * 64;
  float s = 0.f;
#pragma unroll
  for (int d = 0; d < 64; d += 4) {
    float4 zv = *(const float4*)(zp + d);
    float4 cv = *(const float4*)(cp + d);
    s = fmaf(zv.x, cv.x, s); s = fmaf(zv.y, cv.y, s);
    s = fmaf(zv.z, cv.z, s); s = fmaf(zv.w, cv.w, s);
  }
  s += __shfl_xor(s, 1);
  s += __shfl_xor(s, 2);
  float dist = fmaf(-2.f, s, enorm[code]);
  unsigned long long key = ((lane & 3) == 0) ? packdi(dist, code) : ~0ull;
#pragma unroll
  for (int m = 1; m < 64; m <<= 1) key = u64min(key, shflx64(key, m));
  return key;  // wave-uniform
}

// ---- Phase 2: one wave per row over 512 chunk16 maxima (R5 verbatim) -------
__global__ __launch_bounds__(256) void vq_sel(const uint32* __restrict__ bm,
                                              const float* __restrict__ flatz,
                                              const float* __restrict__ cb,
                                              const float* __restrict__ enorm,
                                              float* __restrict__ zq,
                                              float* __restrict__ oidx) {
  const int lane = threadIdx.x & 63;
  const int row = blockIdx.x * 4 + (threadIdx.x >> 6);
  uint4 va = *(const uint4*)(bm + (size_t)row * 512 + lane * 8);
  uint4 vb = *(const uint4*)(bm + (size_t)row * 512 + lane * 8 + 4);
  uint32 v[8] = {va.x, va.y, va.z, va.w, vb.x, vb.y, vb.z, vb.w};
  uint32 m1 = 0, m2 = 0; int ch = 0;
#pragma unroll
  for (int s = 0; s < 8; ++s) {
    uint32 pv = v[s];
    m2 = umax(m2, umin(m1, pv));
    ch = (pv > m1) ? (lane * 8 + s) : ch;
    m1 = umax(m1, pv);
  }
#pragma unroll
  for (int m = 1; m < 64; m <<= 1) {
    uint32 o1 = (uint32)__shfl_xor((int)m1, m);
    uint32 o2 = (uint32)__shfl_xor((int)m2, m);
    int oc = __shfl_xor(ch, m);
    m2 = umax(umax(m2, o2), umin(m1, o1));
    ch = (o1 > m1) ? oc : ch;
    m1 = umax(m1, o1);
  }
  // all wave-uniform now
  float s1 = __uint_as_float(m1 & ~31u);
  float s2 = __uint_as_float(m2 & ~31u);
  int idx;
  if ((m1 & 16u) && (s1 - s2 > SM)) {
    idx = ch * 16 + (int)(m1 & 15u);  // provably the exact argmin
  } else {
    const float* zrow = flatz + (size_t)row * 256;
    unsigned long long key = chunk_exact(ch, zrow, cb, enorm, lane);
    float dbest;
    { unsigned int u = (unsigned int)(key >> 32);
      u = (u & 0x80000000u) ? (u & 0x7FFFFFFFu) : ~u;
      dbest = __uint_as_float(u); }
    float thr = (1024.f - 0.5f * dbest) - EPS_S;  // window lower bound
#pragma unroll
    for (int s = 0; s < 8; ++s) {
      bool cand = __uint_as_float(v[s] & ~31u) >= thr;
      unsigned long long mk = __ballot(cand);
      while (mk) {
        int L = __ffsll(mk) - 1;
        mk &= mk - 1;
        int c2 = L * 8 + s;
        if (c2 == ch) continue;
        key = u64min(key, chunk_exact(c2, zrow, cb, enorm, lane));
      }
    }
    idx = (int)(key & 0xFFFFFFFFull);
  }
  if (lane == 0) oidx[row] = (float)idx;
  float4 val = *(const float4*)(cb + (size_t)idx * 256 + lane * 4);
  *(float4*)(zq + (size_t)row * 256 + lane * 4) = val;  // exact fp32 gather
}

// ---- launch ----------------------------------------------------------------
extern "C" void kernel_launch(void* const* d_in, const int* in_sizes, int n_in,
                              void* d_out, int out_size, void* d_ws, size_t ws_size,
                              hipStream_t stream) {
  const float* z = (const float*)d_in[0];   // (16,256,32,32) fp32
  const float* cb = (const float*)d_in[1];  // (8192,256) fp32
  char* ws = (char*)d_ws;
  // ws: zb 8M@0 | eb 4M@8M | enorm 32K@12M | bm 32M@13M  (45 MB, proven fit)
  ushort* zb = (ushort*)(ws);
  ushort* eb = (ushort*)(ws + (8u << 20));
  float* enorm = (float*)(ws + (12u << 20));
  uint32* bm = (uint32*)(ws + (13u << 20));
  float* zq = (float*)d_out;               // (16384,256) fp32
  float* oidx = zq + (size_t)NROWS * DIM;  // (16384,) as fp32 values
  float* flatz = zq;  // NHWC fp32 z lives in zq until vq_sel overwrites per-row

  prep<<<4096 + NCODES / 4, 256, 0, stream>>>(z, cb, flatz, zb, eb, enorm);
  vq_gemm<<<dim3(NCODES / 128, NROWS / 256), 256, 0, stream>>>(eb, zb, enorm, bm);
  vq_sel<<<NROWS / 4, 256, 0, stream>>>(bm, flatz, cb, enorm, zq, oidx);
}

// Round 8
// 198.588 us; speedup vs baseline: 1.2221x; 1.2221x over previous
//
#include <hip/hip_runtime.h>
#include <stdint.h>

#define NROWS 16384   // 16*32*32 spatial positions
#define NCODES 8192
#define DIM 256
// score = 1024 + dot - ||e||^2/2  (higher = closer). bf16 dist-error sigma
// ~0.05 in score units. EPS_S = 0.4 (8 sigma one-sided); SM = 0.8.
// Validated absmax=0 in R4..R7.
#define EPS_S 0.4f
#define SM 0.8f

typedef __attribute__((ext_vector_type(8))) short bf16x8;    // 8 bf16 = 4 VGPRs
typedef __attribute__((ext_vector_type(16))) float f32x16;   // 32x32 C/D frag
typedef unsigned int uint32;

__device__ __forceinline__ unsigned short f2bf(float f) {
  union { float f; unsigned int u; } v; v.f = f;
  unsigned int u = v.u;
  return (unsigned short)((u + 0x7FFFu + ((u >> 16) & 1u)) >> 16);  // RNE
}

__device__ __forceinline__ void glds16(const void* g, void* l) {
  __builtin_amdgcn_global_load_lds(
      (const __attribute__((address_space(1))) unsigned int*)g,
      (__attribute__((address_space(3))) unsigned int*)l, 16, 0, 0);
}

// exact-path u64 key = order-preserving dist bits << 32 | idx (min = best+lowest idx)
__device__ __forceinline__ unsigned long long packdi(float d, int idx) {
  unsigned int u = __float_as_uint(d);
  u = (u & 0x80000000u) ? ~u : (u | 0x80000000u);
  return ((unsigned long long)u << 32) | (unsigned int)idx;
}
__device__ __forceinline__ unsigned long long u64min(unsigned long long a,
                                                     unsigned long long b) {
  return a < b ? a : b;
}
__device__ __forceinline__ unsigned long long shflx64(unsigned long long v, int m) {
  int lo = __shfl_xor((int)(unsigned int)v, m);
  int hi = __shfl_xor((int)(v >> 32), m);
  return ((unsigned long long)(unsigned int)hi << 32) | (unsigned int)lo;
}
__device__ __forceinline__ uint32 umax(uint32 a, uint32 b) { return a > b ? a : b; }
__device__ __forceinline__ uint32 umin(uint32 a, uint32 b) { return a < b ? a : b; }

// ---- Phase 0 (fused): z transpose+bf16, codebook bf16+norms ----------------
__global__ __launch_bounds__(256) void prep(const float* __restrict__ z,
                                            const float* __restrict__ cb,
                                            float* __restrict__ flatz,
                                            ushort* __restrict__ zb,
                                            ushort* __restrict__ eb,
                                            float* __restrict__ enorm) {
  __shared__ float t[32][33];
  const int blk = blockIdx.x;
  if (blk < 4096) {  // prep_z part: NCHW -> (row, d), fp32 copy into zq
    const int tx = threadIdx.x & 31, ty = threadIdx.x >> 5;  // 32 x 8
    const int ht = blk & 31, ct = (blk >> 5) & 7, b = blk >> 8;
    const float* src = z + (size_t)b * 262144 + (size_t)(ct * 32) * 1024 + ht * 32;
#pragma unroll
    for (int i = 0; i < 4; ++i) {
      int c = ty + i * 8;
      t[c][tx] = src[c * 1024 + tx];
    }
    __syncthreads();
#pragma unroll
    for (int i = 0; i < 4; ++i) {
      int hw = ty + i * 8;
      int row = b * 1024 + ht * 32 + hw;
      float v = t[tx][hw];
      flatz[(size_t)row * 256 + ct * 32 + tx] = v;
      zb[(size_t)row * 256 + ct * 32 + tx] = f2bf(v);
    }
  } else {  // prep_cb part
    const int lane = threadIdx.x & 63, wave = threadIdx.x >> 6;
    const int code = (blk - 4096) * 4 + wave;
    float4 v = *(const float4*)(cb + (size_t)code * 256 + lane * 4);
    ushort4 o;
    o.x = f2bf(v.x); o.y = f2bf(v.y); o.z = f2bf(v.z); o.w = f2bf(v.w);
    *(ushort4*)(eb + (size_t)code * 256 + lane * 4) = o;
    float ss = v.x * v.x + v.y * v.y + v.z * v.z + v.w * v.w;
#pragma unroll
    for (int s = 1; s < 64; s <<= 1) ss += __shfl_xor(ss, s);
    if (lane == 0) enorm[code] = ss;
  }
}

// ---- Phase 1: bf16 MFMA score GEMM — R5 skeleton, 32x32x16 frags -----------
// 128 codes x 128 zrows, A+B LDS dbuf, one barrier/iter (R5: 117 us, 0
// conflicts). 4 waves = 2x2 quadrants of 64x64 = 2i x 2j frags of 32x32.
// Per K-32 iter: 8 MFMA (65 cyc) + 8 ds_read_b128 — same LDS bytes as R5,
// half the MFMA instructions, +20% FLOP/cyc (m119: 2495 vs 2075 TF).
// A/B frag: lane holds row m=lane&31, k = (lane>>5)*8.. (+h*16 per half).
// C/D frag: col=lane&31 (zrow), row=(reg&3)+8*(reg>>2)+4*(lane>>5) [m74/m101].
// Epilogue emits R5's exact bm format: u32 = score&~31 | flag<<4 | id(4b)
// per (zrow, chunk16).
__global__ __launch_bounds__(256) void vq_gemm(const ushort* __restrict__ eb,
                                               const ushort* __restrict__ zb,
                                               const float* __restrict__ enorm,
                                               uint32* __restrict__ bm) {
  __shared__ __align__(16) ushort As[2][4096];  // 2 x (128 codes x 32 k) = 16 KB
  __shared__ __align__(16) ushort Bs[2][4096];  // 2 x (128 zrows x 32 k)
  const int tid = threadIdx.x;
  const int wave = tid >> 6, lane = tid & 63;
  const int wr = wave >> 1, wc = wave & 1;  // code half / zrow half
  const int code0 = blockIdx.x * 128;
  const int zrow0 = blockIdx.y * 128;
  const int l31 = lane & 31, lg = lane >> 5;

  // acc init: 1024 - 0.5*||e||^2 mapped through the 32x32 C/D layout:
  // reg p covers code row (p&3) + 8*(p>>2) + 4*lg of frag i.
  f32x16 acc[2][2];
#pragma unroll
  for (int i = 0; i < 2; ++i) {
    const float* ep = enorm + code0 + wr * 64 + i * 32 + 4 * lg;
    float4 e0 = *(const float4*)(ep);
    float4 e1 = *(const float4*)(ep + 8);
    float4 e2 = *(const float4*)(ep + 16);
    float4 e3 = *(const float4*)(ep + 24);
    f32x16 c0;
    c0[0]  = 1024.f - 0.5f * e0.x; c0[1]  = 1024.f - 0.5f * e0.y;
    c0[2]  = 1024.f - 0.5f * e0.z; c0[3]  = 1024.f - 0.5f * e0.w;
    c0[4]  = 1024.f - 0.5f * e1.x; c0[5]  = 1024.f - 0.5f * e1.y;
    c0[6]  = 1024.f - 0.5f * e1.z; c0[7]  = 1024.f - 0.5f * e1.w;
    c0[8]  = 1024.f - 0.5f * e2.x; c0[9]  = 1024.f - 0.5f * e2.y;
    c0[10] = 1024.f - 0.5f * e2.z; c0[11] = 1024.f - 0.5f * e2.w;
    c0[12] = 1024.f - 0.5f * e3.x; c0[13] = 1024.f - 0.5f * e3.y;
    c0[14] = 1024.f - 0.5f * e3.z; c0[15] = 1024.f - 0.5f * e3.w;
    acc[i][0] = c0; acc[i][1] = c0;
  }

  // staging (R5 verbatim): lane l writes 16B to slot l&3 of row l>>2;
  // global k-chunk = (l&3) ^ ((l>>3)&3)  => layout: slot s of row r holds
  // chunk s ^ ((r>>1)&3)
  const int r_in = lane >> 2;
  const int kc = (lane & 3) ^ ((lane >> 3) & 3);
  const ushort* aG0 = eb + (size_t)(code0 + wave * 16 + r_in) * 256 + kc * 8;
  const ushort* aG1 = eb + (size_t)(code0 + 64 + wave * 16 + r_in) * 256 + kc * 8;
  const ushort* bG0 = zb + (size_t)(zrow0 + wave * 16 + r_in) * 256 + kc * 8;
  const ushort* bG1 = zb + (size_t)(zrow0 + 64 + wave * 16 + r_in) * 256 + kc * 8;

  glds16(aG0, &As[0][wave * 512]);
  glds16(aG1, &As[0][(wave + 4) * 512]);
  glds16(bG0, &Bs[0][wave * 512]);
  glds16(bG1, &Bs[0][(wave + 4) * 512]);

  const int ra = wr * 64 + l31;  // A frag row base (i adds 32)
  const int rb = wc * 64 + l31;  // B frag row base (j adds 32)
  const int hash = (l31 >> 1) & 3;  // (r>>1)&3 — tile bases are mult of 32

#pragma unroll
  for (int k0 = 0; k0 < 8; ++k0) {
    const int cur = k0 & 1;
    __syncthreads();  // drains glds of stage k0; protects buf cur^1 reads
    if (k0 < 7) {
      glds16(aG0 + (k0 + 1) * 32, &As[cur ^ 1][wave * 512]);
      glds16(aG1 + (k0 + 1) * 32, &As[cur ^ 1][(wave + 4) * 512]);
      glds16(bG0 + (k0 + 1) * 32, &Bs[cur ^ 1][wave * 512]);
      glds16(bG1 + (k0 + 1) * 32, &Bs[cur ^ 1][(wave + 4) * 512]);
    }
    bf16x8 af[2][2], bf[2][2];  // [frag][k-half]
#pragma unroll
    for (int i = 0; i < 2; ++i)
#pragma unroll
      for (int h = 0; h < 2; ++h) {
        int slot = (h * 2 + lg) ^ hash;
        af[i][h] = *(const bf16x8*)(&As[cur][(ra + i * 32) * 32 + slot * 8]);
        bf[i][h] = *(const bf16x8*)(&Bs[cur][(rb + i * 32) * 32 + slot * 8]);
      }
#pragma unroll
    for (int h = 0; h < 2; ++h)
#pragma unroll
      for (int i = 0; i < 2; ++i)
#pragma unroll
        for (int j = 0; j < 2; ++j)
          acc[i][j] = __builtin_amdgcn_mfma_f32_32x32x16_bf16(
              af[i][h], bf[j][h], acc[i][j], 0, 0, 0);
  }

  // epilogue: per (i,j) frag each lane holds 16 codes of one zrow; regs
  // hc*8+p cover chunk16 hc with code-in-chunk id = (p&3) | lg<<2 | (p>>2)<<3.
  // Top-2 chain over 8 regs, one cross-lane merge (lane^32), flag bit 4 =
  // in-chunk gap > SM. bm format identical to R5 (vq_sel unchanged).
  const int cid0 = blockIdx.x * 8 + wr * 4;
#pragma unroll
  for (int j = 0; j < 2; ++j) {
    uint32 res[4];
#pragma unroll
    for (int i = 0; i < 2; ++i)
#pragma unroll
      for (int hc = 0; hc < 2; ++hc) {
        uint32 m1 = 0, m2 = 0;
#pragma unroll
        for (int p = 0; p < 8; ++p) {
          uint32 id = (uint32)((p & 3) | (lg << 2) | ((p >> 2) << 3));
          uint32 pv = (__float_as_uint(acc[i][j][hc * 8 + p]) & ~31u) | id;
          m2 = umax(m2, umin(m1, pv));
          m1 = umax(m1, pv);
        }
        uint32 o1 = (uint32)__shfl_xor((int)m1, 32);
        uint32 o2 = (uint32)__shfl_xor((int)m2, 32);
        m2 = umax(umax(m2, o2), umin(m1, o1));
        m1 = umax(m1, o1);
        float s1 = __uint_as_float(m1 & ~31u);
        float s2 = __uint_as_float(m2 & ~31u);
        res[i * 2 + hc] = (s1 - s2 > SM) ? (m1 | 16u) : m1;
      }
    if (lane < 32) {
      int zr = zrow0 + wc * 64 + j * 32 + l31;
      uint4 o; o.x = res[0]; o.y = res[1]; o.z = res[2]; o.w = res[3];
      *(uint4*)(bm + (size_t)zr * 512 + cid0) = o;
    }
  }
}

// exact fp32 distances for one 16-code chunk; summation order / lane split /
// tie-break bit-identical to the R2..R7-validated slow path.
__device__ __forceinline__ unsigned long long chunk_exact(
    int chunk, const float* __restrict__ zrow, const float* __restrict__ cb,
    const float* __restrict__ enorm, int lane) {
  const int code = chunk * 16 + (lane >> 2);
  const float* zp = zrow + (lane & 3) * 64;
  const float* cp = cb + (size_t)code * 256 + (lane & 3) * 64;
  float s = 0.f;
#pragma unroll
  for (int d = 0; d < 64; d += 4) {
    float4 zv = *(const float4*)(zp + d);
    float4 cv = *(const float4*)(cp + d);
    s = fmaf(zv.x, cv.x, s); s = fmaf(zv.y, cv.y, s);
    s = fmaf(zv.z, cv.z, s); s = fmaf(zv.w, cv.w, s);
  }
  s += __shfl_xor(s, 1);
  s += __shfl_xor(s, 2);
  float dist = fmaf(-2.f, s, enorm[code]);
  unsigned long long key = ((lane & 3) == 0) ? packdi(dist, code) : ~0ull;
#pragma unroll
  for (int m = 1; m < 64; m <<= 1) key = u64min(key, shflx64(key, m));
  return key;  // wave-uniform
}

// ---- Phase 2: one wave per row over 512 chunk16 maxima (R5 verbatim) -------
__global__ __launch_bounds__(256) void vq_sel(const uint32* __restrict__ bm,
                                              const float* __restrict__ flatz,
                                              const float* __restrict__ cb,
                                              const float* __restrict__ enorm,
                                              float* __restrict__ zq,
                                              float* __restrict__ oidx) {
  const int lane = threadIdx.x & 63;
  const int row = blockIdx.x * 4 + (threadIdx.x >> 6);
  uint4 va = *(const uint4*)(bm + (size_t)row * 512 + lane * 8);
  uint4 vb = *(const uint4*)(bm + (size_t)row * 512 + lane * 8 + 4);
  uint32 v[8] = {va.x, va.y, va.z, va.w, vb.x, vb.y, vb.z, vb.w};
  uint32 m1 = 0, m2 = 0; int ch = 0;
#pragma unroll
  for (int s = 0; s < 8; ++s) {
    uint32 pv = v[s];
    m2 = umax(m2, umin(m1, pv));
    ch = (pv > m1) ? (lane * 8 + s) : ch;
    m1 = umax(m1, pv);
  }
#pragma unroll
  for (int m = 1; m < 64; m <<= 1) {
    uint32 o1 = (uint32)__shfl_xor((int)m1, m);
    uint32 o2 = (uint32)__shfl_xor((int)m2, m);
    int oc = __shfl_xor(ch, m);
    m2 = umax(umax(m2, o2), umin(m1, o1));
    ch = (o1 > m1) ? oc : ch;
    m1 = umax(m1, o1);
  }
  // all wave-uniform now
  float s1 = __uint_as_float(m1 & ~31u);
  float s2 = __uint_as_float(m2 & ~31u);
  int idx;
  if ((m1 & 16u) && (s1 - s2 > SM)) {
    idx = ch * 16 + (int)(m1 & 15u);  // provably the exact argmin
  } else {
    const float* zrow = flatz + (size_t)row * 256;
    unsigned long long key = chunk_exact(ch, zrow, cb, enorm, lane);
    float dbest;
    { unsigned int u = (unsigned int)(key >> 32);
      u = (u & 0x80000000u) ? (u & 0x7FFFFFFFu) : ~u;
      dbest = __uint_as_float(u); }
    float thr = (1024.f - 0.5f * dbest) - EPS_S;  // window lower bound
#pragma unroll
    for (int s = 0; s < 8; ++s) {
      bool cand = __uint_as_float(v[s] & ~31u) >= thr;
      unsigned long long mk = __ballot(cand);
      while (mk) {
        int L = __ffsll(mk) - 1;
        mk &= mk - 1;
        int c2 = L * 8 + s;
        if (c2 == ch) continue;
        key = u64min(key, chunk_exact(c2, zrow, cb, enorm, lane));
      }
    }
    idx = (int)(key & 0xFFFFFFFFull);
  }
  if (lane == 0) oidx[row] = (float)idx;
  float4 val = *(const float4*)(cb + (size_t)idx * 256 + lane * 4);
  *(float4*)(zq + (size_t)row * 256 + lane * 4) = val;  // exact fp32 gather
}

// ---- launch ----------------------------------------------------------------
extern "C" void kernel_launch(void* const* d_in, const int* in_sizes, int n_in,
                              void* d_out, int out_size, void* d_ws, size_t ws_size,
                              hipStream_t stream) {
  const float* z = (const float*)d_in[0];   // (16,256,32,32) fp32
  const float* cb = (const float*)d_in[1];  // (8192,256) fp32
  char* ws = (char*)d_ws;
  // ws: zb 8M@0 | eb 4M@8M | enorm 32K@12M | bm 32M@13M  (45 MB, proven fit)
  ushort* zb = (ushort*)(ws);
  ushort* eb = (ushort*)(ws + (8u << 20));
  float* enorm = (float*)(ws + (12u << 20));
  uint32* bm = (uint32*)(ws + (13u << 20));
  float* zq = (float*)d_out;               // (16384,256) fp32
  float* oidx = zq + (size_t)NROWS * DIM;  // (16384,) as fp32 values
  float* flatz = zq;  // NHWC fp32 z lives in zq until vq_sel overwrites per-row

  prep<<<4096 + NCODES / 4, 256, 0, stream>>>(z, cb, flatz, zb, eb, enorm);
  vq_gemm<<<dim3(NCODES / 128, NROWS / 128), 256, 0, stream>>>(eb, zb, enorm, bm);
  vq_sel<<<NROWS / 4, 256, 0, stream>>>(bm, flatz, cb, enorm, zq, oidx);
}

// Round 9
// 193.123 us; speedup vs baseline: 1.2567x; 1.0283x over previous
//
#include <hip/hip_runtime.h>
#include <stdint.h>

#define NROWS 16384   // 16*32*32 spatial positions
#define NCODES 8192
#define DIM 256
// score = 1024 + dot - ||e||^2/2  (higher = closer). bf16 dist-error sigma
// ~0.05 in score units. EPS_S = 0.4 (8 sigma one-sided); SM = 0.8.
// Validated absmax=0 in R4..R8.
#define EPS_S 0.4f
#define SM 0.8f

typedef __attribute__((ext_vector_type(8))) short bf16x8;    // 8 bf16 = 4 VGPRs
typedef __attribute__((ext_vector_type(16))) float f32x16;   // 32x32 C/D frag
typedef unsigned int uint32;

__device__ __forceinline__ unsigned short f2bf(float f) {
  union { float f; unsigned int u; } v; v.f = f;
  unsigned int u = v.u;
  return (unsigned short)((u + 0x7FFFu + ((u >> 16) & 1u)) >> 16);  // RNE
}

// exact-path u64 key = order-preserving dist bits << 32 | idx (min = best+lowest idx)
__device__ __forceinline__ unsigned long long packdi(float d, int idx) {
  unsigned int u = __float_as_uint(d);
  u = (u & 0x80000000u) ? ~u : (u | 0x80000000u);
  return ((unsigned long long)u << 32) | (unsigned int)idx;
}
__device__ __forceinline__ unsigned long long u64min(unsigned long long a,
                                                     unsigned long long b) {
  return a < b ? a : b;
}
__device__ __forceinline__ unsigned long long shflx64(unsigned long long v, int m) {
  int lo = __shfl_xor((int)(unsigned int)v, m);
  int hi = __shfl_xor((int)(v >> 32), m);
  return ((unsigned long long)(unsigned int)hi << 32) | (unsigned int)lo;
}
__device__ __forceinline__ uint32 umax(uint32 a, uint32 b) { return a > b ? a : b; }
__device__ __forceinline__ uint32 umin(uint32 a, uint32 b) { return a < b ? a : b; }

// ---- Phase 0 (fused): z transpose+bf16, codebook bf16+norms ----------------
__global__ __launch_bounds__(256) void prep(const float* __restrict__ z,
                                            const float* __restrict__ cb,
                                            float* __restrict__ flatz,
                                            ushort* __restrict__ zb,
                                            ushort* __restrict__ eb,
                                            float* __restrict__ enorm) {
  __shared__ float t[32][33];
  const int blk = blockIdx.x;
  if (blk < 4096) {  // prep_z part: NCHW -> (row, d), fp32 copy into zq
    const int tx = threadIdx.x & 31, ty = threadIdx.x >> 5;  // 32 x 8
    const int ht = blk & 31, ct = (blk >> 5) & 7, b = blk >> 8;
    const float* src = z + (size_t)b * 262144 + (size_t)(ct * 32) * 1024 + ht * 32;
#pragma unroll
    for (int i = 0; i < 4; ++i) {
      int c = ty + i * 8;
      t[c][tx] = src[c * 1024 + tx];
    }
    __syncthreads();
#pragma unroll
    for (int i = 0; i < 4; ++i) {
      int hw = ty + i * 8;
      int row = b * 1024 + ht * 32 + hw;
      float v = t[tx][hw];
      flatz[(size_t)row * 256 + ct * 32 + tx] = v;
      zb[(size_t)row * 256 + ct * 32 + tx] = f2bf(v);
    }
  } else {  // prep_cb part
    const int lane = threadIdx.x & 63, wave = threadIdx.x >> 6;
    const int code = (blk - 4096) * 4 + wave;
    float4 v = *(const float4*)(cb + (size_t)code * 256 + lane * 4);
    ushort4 o;
    o.x = f2bf(v.x); o.y = f2bf(v.y); o.z = f2bf(v.z); o.w = f2bf(v.w);
    *(ushort4*)(eb + (size_t)code * 256 + lane * 4) = o;
    float ss = v.x * v.x + v.y * v.y + v.z * v.z + v.w * v.w;
#pragma unroll
    for (int s = 1; s < 64; s <<= 1) ss += __shfl_xor(ss, s);
    if (lane == 0) enorm[code] = ss;
  }
}

// ---- Phase 1: bf16 MFMA score GEMM — software-pipelined staging ------------
// R8 structure (128x128 tile, 32x32x16 frags, dbuf LDS) with the glds
// staging replaced by a depth-2 register pipeline:
//   iter k: issue global loads for stage k+2 -> VGPRs (in flight all iter);
//           ds_write stage k+1 from regs loaded last iter (vmcnt wait: free);
//           ds_read + MFMA on stage k; __syncthreads.
// The barrier's vmcnt(0) drain now targets loads issued a full iteration
// earlier (mostly complete) instead of glds issued ~150 cyc earlier — this
// attacks the measured stall that pinned R3/R5/R8 at ~115 us.
__global__ __launch_bounds__(256) void vq_gemm(const ushort* __restrict__ eb,
                                               const ushort* __restrict__ zb,
                                               const float* __restrict__ enorm,
                                               uint32* __restrict__ bm) {
  __shared__ __align__(16) ushort As[2][4096];  // 2 x (128 codes x 32 k) = 16 KB
  __shared__ __align__(16) ushort Bs[2][4096];  // 2 x (128 zrows x 32 k)
  const int tid = threadIdx.x;
  const int wave = tid >> 6, lane = tid & 63;
  const int wr = wave >> 1, wc = wave & 1;  // code half / zrow half
  const int code0 = blockIdx.x * 128;
  const int zrow0 = blockIdx.y * 128;
  const int l31 = lane & 31, lg = lane >> 5;

  // acc init: 1024 - 0.5*||e||^2 through the 32x32 C/D layout:
  // reg p covers code row (p&3) + 8*(p>>2) + 4*lg of frag i  [m74/m101].
  f32x16 acc[2][2];
#pragma unroll
  for (int i = 0; i < 2; ++i) {
    const float* ep = enorm + code0 + wr * 64 + i * 32 + 4 * lg;
    float4 e0 = *(const float4*)(ep);
    float4 e1 = *(const float4*)(ep + 8);
    float4 e2 = *(const float4*)(ep + 16);
    float4 e3 = *(const float4*)(ep + 24);
    f32x16 c0;
    c0[0]  = 1024.f - 0.5f * e0.x; c0[1]  = 1024.f - 0.5f * e0.y;
    c0[2]  = 1024.f - 0.5f * e0.z; c0[3]  = 1024.f - 0.5f * e0.w;
    c0[4]  = 1024.f - 0.5f * e1.x; c0[5]  = 1024.f - 0.5f * e1.y;
    c0[6]  = 1024.f - 0.5f * e1.z; c0[7]  = 1024.f - 0.5f * e1.w;
    c0[8]  = 1024.f - 0.5f * e2.x; c0[9]  = 1024.f - 0.5f * e2.y;
    c0[10] = 1024.f - 0.5f * e2.z; c0[11] = 1024.f - 0.5f * e2.w;
    c0[12] = 1024.f - 0.5f * e3.x; c0[13] = 1024.f - 0.5f * e3.y;
    c0[14] = 1024.f - 0.5f * e3.z; c0[15] = 1024.f - 0.5f * e3.w;
    acc[i][0] = c0; acc[i][1] = c0;
  }

  // staging addressing (R8 layout): slot s of row r holds chunk s^((r>>1)&3);
  // lane l covers row l>>2, slot l&3 -> global chunk (l&3)^((l>>3)&3).
  const int r_in = lane >> 2;
  const int kc = (lane & 3) ^ ((lane >> 3) & 3);
  const ushort* aG0 = eb + (size_t)(code0 + wave * 16 + r_in) * 256 + kc * 8;
  const ushort* aG1 = eb + (size_t)(code0 + 64 + wave * 16 + r_in) * 256 + kc * 8;
  const ushort* bG0 = zb + (size_t)(zrow0 + wave * 16 + r_in) * 256 + kc * 8;
  const ushort* bG1 = zb + (size_t)(zrow0 + 64 + wave * 16 + r_in) * 256 + kc * 8;
  // LDS write slots (ushort units): linear 16B per lane, same layout glds used
  const int wo0 = wave * 512 + lane * 8;
  const int wo1 = (wave + 4) * 512 + lane * 8;

  // prologue: stage0 + stage1 -> regs; stage0 -> LDS buf0
  bf16x8 pa[2], pb[2], na[2], nb[2];
  pa[0] = *(const bf16x8*)(aG0);        pa[1] = *(const bf16x8*)(aG1);
  pb[0] = *(const bf16x8*)(bG0);        pb[1] = *(const bf16x8*)(bG1);
  na[0] = *(const bf16x8*)(aG0 + 32);   na[1] = *(const bf16x8*)(aG1 + 32);
  nb[0] = *(const bf16x8*)(bG0 + 32);   nb[1] = *(const bf16x8*)(bG1 + 32);
  *(bf16x8*)(&As[0][wo0]) = pa[0];
  *(bf16x8*)(&As[0][wo1]) = pa[1];
  *(bf16x8*)(&Bs[0][wo0]) = pb[0];
  *(bf16x8*)(&Bs[0][wo1]) = pb[1];
  __syncthreads();  // stage 0 visible; stage 1 loads still in flight

  const int ra = wr * 64 + l31;  // A frag row base (i adds 32)
  const int rb = wc * 64 + l31;  // B frag row base (j adds 32)
  const int hash = (l31 >> 1) & 3;

#pragma unroll
  for (int k0 = 0; k0 < 8; ++k0) {
    const int cur = k0 & 1;
    // 1) deep prefetch: stage k0+2 -> regs (clamped; tail re-load harmless)
    const int kn = (k0 + 2 <= 7) ? (k0 + 2) : 7;
    bf16x8 qa0 = *(const bf16x8*)(aG0 + kn * 32);
    bf16x8 qa1 = *(const bf16x8*)(aG1 + kn * 32);
    bf16x8 qb0 = *(const bf16x8*)(bG0 + kn * 32);
    bf16x8 qb1 = *(const bf16x8*)(bG1 + kn * 32);
    // 2) stage k0+1 regs -> LDS buf cur^1 (vmcnt wait: loads from iter k0-1)
    if (k0 < 7) {
      *(bf16x8*)(&As[cur ^ 1][wo0]) = na[0];
      *(bf16x8*)(&As[cur ^ 1][wo1]) = na[1];
      *(bf16x8*)(&Bs[cur ^ 1][wo0]) = nb[0];
      *(bf16x8*)(&Bs[cur ^ 1][wo1]) = nb[1];
    }
    // 3) compute on stage k0
    bf16x8 af[2][2], bf[2][2];  // [frag][k-half]
#pragma unroll
    for (int i = 0; i < 2; ++i)
#pragma unroll
      for (int h = 0; h < 2; ++h) {
        int slot = (h * 2 + lg) ^ hash;
        af[i][h] = *(const bf16x8*)(&As[cur][(ra + i * 32) * 32 + slot * 8]);
        bf[i][h] = *(const bf16x8*)(&Bs[cur][(rb + i * 32) * 32 + slot * 8]);
      }
#pragma unroll
    for (int h = 0; h < 2; ++h)
#pragma unroll
      for (int i = 0; i < 2; ++i)
#pragma unroll
        for (int j = 0; j < 2; ++j)
          acc[i][j] = __builtin_amdgcn_mfma_f32_32x32x16_bf16(
              af[i][h], bf[j][h], acc[i][j], 0, 0, 0);
    // 4) rotate pipeline regs
    na[0] = qa0; na[1] = qa1; nb[0] = qb0; nb[1] = qb1;
    __syncthreads();  // drains: ds_writes (fast) + loads issued at iter start
  }

  // epilogue (R8 verbatim): per (i,j) frag lane holds 16 codes of one zrow;
  // regs hc*8+p cover chunk16 hc, id = (p&3) | lg<<2 | (p>>2)<<3. Top-2 via
  // u32 chains + one cross-lane merge; flag bit 4 = in-chunk gap > SM.
  const int cid0 = blockIdx.x * 8 + wr * 4;
#pragma unroll
  for (int j = 0; j < 2; ++j) {
    uint32 res[4];
#pragma unroll
    for (int i = 0; i < 2; ++i)
#pragma unroll
      for (int hc = 0; hc < 2; ++hc) {
        uint32 m1 = 0, m2 = 0;
#pragma unroll
        for (int p = 0; p < 8; ++p) {
          uint32 id = (uint32)((p & 3) | (lg << 2) | ((p >> 2) << 3));
          uint32 pv = (__float_as_uint(acc[i][j][hc * 8 + p]) & ~31u) | id;
          m2 = umax(m2, umin(m1, pv));
          m1 = umax(m1, pv);
        }
        uint32 o1 = (uint32)__shfl_xor((int)m1, 32);
        uint32 o2 = (uint32)__shfl_xor((int)m2, 32);
        m2 = umax(umax(m2, o2), umin(m1, o1));
        m1 = umax(m1, o1);
        float s1 = __uint_as_float(m1 & ~31u);
        float s2 = __uint_as_float(m2 & ~31u);
        res[i * 2 + hc] = (s1 - s2 > SM) ? (m1 | 16u) : m1;
      }
    if (lane < 32) {
      int zr = zrow0 + wc * 64 + j * 32 + l31;
      uint4 o; o.x = res[0]; o.y = res[1]; o.z = res[2]; o.w = res[3];
      *(uint4*)(bm + (size_t)zr * 512 + cid0) = o;
    }
  }
}

// exact fp32 distances for one 16-code chunk; summation order / lane split /
// tie-break bit-identical to the R2..R8-validated slow path.
__device__ __forceinline__ unsigned long long chunk_exact(
    int chunk, const float* __restrict__ zrow, const float* __restrict__ cb,
    const float* __restrict__ enorm, int lane) {
  const int code = chunk * 16 + (lane >> 2);
  const float* zp = zrow + (lane & 3) * 64;
  const float* cp = cb + (size_t)code * 256 + (lane & 3) * 64;
  float s = 0.f;
#pragma unroll
  for (int d = 0; d < 64; d += 4) {
    float4 zv = *(const float4*)(zp + d);
    float4 cv = *(const float4*)(cp + d);
    s = fmaf(zv.x, cv.x, s); s = fmaf(zv.y, cv.y, s);
    s = fmaf(zv.z, cv.z, s); s = fmaf(zv.w, cv.w, s);
  }
  s += __shfl_xor(s, 1);
  s += __shfl_xor(s, 2);
  float dist = fmaf(-2.f, s, enorm[code]);
  unsigned long long key = ((lane & 3) == 0) ? packdi(dist, code) : ~0ull;
#pragma unroll
  for (int m = 1; m < 64; m <<= 1) key = u64min(key, shflx64(key, m));
  return key;  // wave-uniform
}

// ---- Phase 2: one wave per row over 512 chunk16 maxima (R5/R8 verbatim) ----
__global__ __launch_bounds__(256) void vq_sel(const uint32* __restrict__ bm,
                                              const float* __restrict__ flatz,
                                              const float* __restrict__ cb,
                                              const float* __restrict__ enorm,
                                              float* __restrict__ zq,
                                              float* __restrict__ oidx) {
  const int lane = threadIdx.x & 63;
  const int row = blockIdx.x * 4 + (threadIdx.x >> 6);
  uint4 va = *(const uint4*)(bm + (size_t)row * 512 + lane * 8);
  uint4 vb = *(const uint4*)(bm + (size_t)row * 512 + lane * 8 + 4);
  uint32 v[8] = {va.x, va.y, va.z, va.w, vb.x, vb.y, vb.z, vb.w};
  uint32 m1 = 0, m2 = 0; int ch = 0;
#pragma unroll
  for (int s = 0; s < 8; ++s) {
    uint32 pv = v[s];
    m2 = umax(m2, umin(m1, pv));
    ch = (pv > m1) ? (lane * 8 + s) : ch;
    m1 = umax(m1, pv);
  }
#pragma unroll
  for (int m = 1; m < 64; m <<= 1) {
    uint32 o1 = (uint32)__shfl_xor((int)m1, m);
    uint32 o2 = (uint32)__shfl_xor((int)m2, m);
    int oc = __shfl_xor(ch, m);
    m2 = umax(umax(m2, o2), umin(m1, o1));
    ch = (o1 > m1) ? oc : ch;
    m1 = umax(m1, o1);
  }
  // all wave-uniform now
  float s1 = __uint_as_float(m1 & ~31u);
  float s2 = __uint_as_float(m2 & ~31u);
  int idx;
  if ((m1 & 16u) && (s1 - s2 > SM)) {
    idx = ch * 16 + (int)(m1 & 15u);  // provably the exact argmin
  } else {
    const float* zrow = flatz + (size_t)row * 256;
    unsigned long long key = chunk_exact(ch, zrow, cb, enorm, lane);
    float dbest;
    { unsigned int u = (unsigned int)(key >> 32);
      u = (u & 0x80000000u) ? (u & 0x7FFFFFFFu) : ~u;
      dbest = __uint_as_float(u); }
    float thr = (1024.f - 0.5f * dbest) - EPS_S;  // window lower bound
#pragma unroll
    for (int s = 0; s < 8; ++s) {
      bool cand = __uint_as_float(v[s] & ~31u) >= thr;
      unsigned long long mk = __ballot(cand);
      while (mk) {
        int L = __ffsll(mk) - 1;
        mk &= mk - 1;
        int c2 = L * 8 + s;
        if (c2 == ch) continue;
        key = u64min(key, chunk_exact(c2, zrow, cb, enorm, lane));
      }
    }
    idx = (int)(key & 0xFFFFFFFFull);
  }
  if (lane == 0) oidx[row] = (float)idx;
  float4 val = *(const float4*)(cb + (size_t)idx * 256 + lane * 4);
  *(float4*)(zq + (size_t)row * 256 + lane * 4) = val;  // exact fp32 gather
}

// ---- launch ----------------------------------------------------------------
extern "C" void kernel_launch(void* const* d_in, const int* in_sizes, int n_in,
                              void* d_out, int out_size, void* d_ws, size_t ws_size,
                              hipStream_t stream) {
  const float* z = (const float*)d_in[0];   // (16,256,32,32) fp32
  const float* cb = (const float*)d_in[1];  // (8192,256) fp32
  char* ws = (char*)d_ws;
  // ws: zb 8M@0 | eb 4M@8M | enorm 32K@12M | bm 32M@13M  (45 MB, proven fit)
  ushort* zb = (ushort*)(ws);
  ushort* eb = (ushort*)(ws + (8u << 20));
  float* enorm = (float*)(ws + (12u << 20));
  uint32* bm = (uint32*)(ws + (13u << 20));
  float* zq = (float*)d_out;               // (16384,256) fp32
  float* oidx = zq + (size_t)NROWS * DIM;  // (16384,) as fp32 values
  float* flatz = zq;  // NHWC fp32 z lives in zq until vq_sel overwrites per-row

  prep<<<4096 + NCODES / 4, 256, 0, stream>>>(z, cb, flatz, zb, eb, enorm);
  vq_gemm<<<dim3(NCODES / 128, NROWS / 128), 256, 0, stream>>>(eb, zb, enorm, bm);
  vq_sel<<<NROWS / 4, 256, 0, stream>>>(bm, flatz, cb, enorm, zq, oidx);
}